// Round 1
// baseline (1080.912 us; speedup 1.0000x reference)
//
#include <hip/hip_runtime.h>
#include <hip/hip_bf16.h>
#include <stdint.h>

// B=4, N=256, H=D=256.  M = N*N = 65536 edges per batch.
#define NB 4
#define NN 256
#define DD 256
#define MM 65536

typedef __attribute__((ext_vector_type(8))) __bf16 bf16x8;
typedef __attribute__((ext_vector_type(4))) __bf16 bf16x4;
typedef __attribute__((ext_vector_type(4))) float f32x4;

__device__ __forceinline__ f32x4 mfma_bf16(bf16x8 a, bf16x8 b, f32x4 c) {
    return __builtin_amdgcn_mfma_f32_16x16x32_bf16(a, b, c, 0, 0, 0);
}

// XOR-swizzled LDS indices (8-element groups xor'd by low-3 bits of row) so
// both the b128 fragment reads and the transpose writes are conflict-free
// without padding (keeps total LDS at exactly 64 KB -> 2 WGs/CU).
__device__ __forceinline__ int sidx(int row, int e) {      // Sb[64][256]
    return row * 256 + ((((e >> 3) ^ row) & 7) << 3) + (e & 7)
           + ((e >> 3) & ~7) * 8 - ((((e >> 3)) & ~7) << 3);  // == row*256 + ((e>>3 ^ (row&7))<<3) + (e&7)
}
__device__ __forceinline__ int sidx2(int row, int e) {
    return row * 256 + (((e >> 3) ^ (row & 7)) << 3) + (e & 7);
}
__device__ __forceinline__ int tidx(int n, int m) {        // Tb[256][64]
    return n * 64 + (((m >> 3) ^ (n & 7)) << 3) + (m & 7);
}

// ---------------- tiny precompute kernels ----------------

__global__ void zero_kernel(float* __restrict__ p) {
    reinterpret_cast<float4*>(p)[blockIdx.x * 256 + threadIdx.x] =
        make_float4(0.f, 0.f, 0.f, 0.f);
}

// k[row,d] = hidden[row,:] @ Wk[:,d] + bk[d]
__global__ void kproj_kernel(const float* __restrict__ hs, const float* __restrict__ Wk,
                             const float* __restrict__ bk, float* __restrict__ kf) {
    const int row = blockIdx.x, t = threadIdx.x;
    __shared__ float hr[256];
    hr[t] = hs[(size_t)row * 256 + t];
    __syncthreads();
    float v = bk[t];
    for (int e = 0; e < 256; ++e)
        v = fmaf(hr[e], Wk[(size_t)e * 256 + t], v);
    kf[(size_t)row * 256 + t] = v;
}

// kq[row,e] = (sum_d Wq[e,d] * k[row,d]) / 16 ;  cb[row] = (bq . k[row]) / 16
__global__ void kqprep_kernel(const float* __restrict__ kf, const float* __restrict__ Wq,
                              const float* __restrict__ bq, __bf16* __restrict__ kq,
                              float* __restrict__ cb) {
    const int row = blockIdx.x, t = threadIdx.x;
    __shared__ float kr[256];
    __shared__ float red[256];
    float kv = kf[(size_t)row * 256 + t];
    kr[t] = kv;
    red[t] = kv * bq[t];
    __syncthreads();
    float v = 0.f;
    for (int d = 0; d < 256; ++d)
        v = fmaf(Wq[(size_t)t * 256 + d], kr[d], v);
    kq[(size_t)row * 256 + t] = (__bf16)(v * 0.0625f);
    for (int s = 128; s > 0; s >>= 1) {
        if (t < s) red[t] += red[t + s];
        __syncthreads();
    }
    if (t == 0) cb[row] = red[0] * 0.0625f;
}

// wvoT[h,e] = sum_d Wv[e,d] * Wo[d,h] ;  bvo[h] = sum_d bv[d] * Wo[d,h]
__global__ void wvoprep_kernel(const float* __restrict__ Wv, const float* __restrict__ Wo,
                               const float* __restrict__ bv, __bf16* __restrict__ wvoT,
                               float* __restrict__ bvo) {
    const int h = blockIdx.x, t = threadIdx.x;
    __shared__ float woc[256];
    __shared__ float red[256];
    float wo = Wo[(size_t)t * 256 + h];
    woc[t] = wo;
    red[t] = bv[t] * wo;
    __syncthreads();
    float v = 0.f;
    for (int d = 0; d < 256; ++d)
        v = fmaf(Wv[(size_t)t * 256 + d], woc[d], v);
    wvoT[(size_t)h * 256 + t] = (__bf16)v;
    for (int s = 128; s > 0; s >>= 1) {
        if (t < s) red[t] += red[t + s];
        __syncthreads();
    }
    if (t == 0) bvo[h] = red[0];
}

// ---------------- phase A: scores -> probs, vo; write P^T / VO^T ----------------
// One WG = 4 waves = 64 edge-rows. Wave w owns rows [w*16, w*16+16).
__global__ __launch_bounds__(256, 2)
void phaseA_kernel(const float* __restrict__ S, const __bf16* __restrict__ kq,
                   const float* __restrict__ cb, const __bf16* __restrict__ wvoT,
                   const float* __restrict__ bvo, const float* __restrict__ mask,
                   __bf16* __restrict__ PT, __bf16* __restrict__ VOT,
                   int b, int c0, int CH) {
    __shared__ __align__(16) __bf16 Sb[64 * 256];   // 32 KB
    __shared__ __align__(16) __bf16 Tb[256 * 64];   // 32 KB (transpose staging)
    const int t = threadIdx.x;
    const int w = t >> 6;
    const int lane = t & 63;
    const int q = lane >> 4;
    const int ln = lane & 15;
    const int m0 = c0 + blockIdx.x * 64;

    // stage S tile (64 x 256) -> bf16 LDS, coalesced float4 loads
    const float* Sg = S + ((size_t)b * MM + m0) * DD;
    for (int it = 0; it < 16; ++it) {
        int idx = it * 256 + t;
        int row = idx >> 6;
        int c4 = idx & 63;
        float4 v = reinterpret_cast<const float4*>(Sg)[row * 64 + c4];
        bf16x4 bv = { (__bf16)v.x, (__bf16)v.y, (__bf16)v.z, (__bf16)v.w };
        *reinterpret_cast<bf16x4*>(&Sb[sidx2(row, c4 * 4)]) = bv;
    }
    __syncthreads();

    const int mr = w * 16;
    bf16x8 af[8];
#pragma unroll
    for (int kk = 0; kk < 8; ++kk)
        af[kk] = *reinterpret_cast<const bf16x8*>(&Sb[sidx2(mr + ln, kk * 32 + q * 8)]);

    // scores GEMM: scores[m,n] = S[m,:] . kq[n,:]   (K=256)
    f32x4 acc[16];
#pragma unroll
    for (int nt = 0; nt < 16; ++nt) {
        f32x4 a = {0.f, 0.f, 0.f, 0.f};
        const __bf16* kqr = kq + ((size_t)b * NN + nt * 16 + ln) * DD + q * 8;
#pragma unroll
        for (int kk = 0; kk < 8; ++kk) {
            bf16x8 bf = *reinterpret_cast<const bf16x8*>(kqr + kk * 32);
            a = mfma_bf16(af[kk], bf, a);
        }
        acc[nt] = a;
    }

    // + cb[n] + pairwise mask, relu, row-sum over n, normalize
    float m2[4];
#pragma unroll
    for (int r = 0; r < 4; ++r) {
        int mg = m0 + mr + q * 4 + r;
        m2[r] = mask[b * NN + (mg >> 8)] * mask[b * NN + (mg & 255)];
    }
    float rs0 = 0.f, rs1 = 0.f, rs2 = 0.f, rs3 = 0.f;
#pragma unroll
    for (int nt = 0; nt < 16; ++nt) {
        float cbv = cb[b * NN + nt * 16 + ln];
        f32x4 a = acc[nt];
        a.x = fmaxf(a.x + cbv + m2[0], 0.f);
        a.y = fmaxf(a.y + cbv + m2[1], 0.f);
        a.z = fmaxf(a.z + cbv + m2[2], 0.f);
        a.w = fmaxf(a.w + cbv + m2[3], 0.f);
        acc[nt] = a;
        rs0 += a.x; rs1 += a.y; rs2 += a.z; rs3 += a.w;
    }
#pragma unroll
    for (int off = 1; off < 16; off <<= 1) {   // reduce across the 16 lanes of each quad-row group
        rs0 += __shfl_xor(rs0, off);
        rs1 += __shfl_xor(rs1, off);
        rs2 += __shfl_xor(rs2, off);
        rs3 += __shfl_xor(rs3, off);
    }
    // ref: probs / sum(probs + 1e-12, axis=-1) == probs / (rowsum + 256e-12)
    const float i0 = 1.f / (rs0 + 2.56e-10f);
    const float i1 = 1.f / (rs1 + 2.56e-10f);
    const float i2 = 1.f / (rs2 + 2.56e-10f);
    const float i3 = 1.f / (rs3 + 2.56e-10f);
#pragma unroll
    for (int nt = 0; nt < 16; ++nt) {
        f32x4 a = acc[nt];
        bf16x4 pv = { (__bf16)(a.x * i0), (__bf16)(a.y * i1),
                      (__bf16)(a.z * i2), (__bf16)(a.w * i3) };
        *reinterpret_cast<bf16x4*>(&Tb[tidx(nt * 16 + ln, mr + q * 4)]) = pv;
    }
    __syncthreads();
    {   // flush P^T tile: PT[n][m0-c0 .. +64)
        __bf16* Pg = PT + (m0 - c0);
        for (int it = 0; it < 32; ++it) {
            int idx = it * 256 + t;
            int n = idx >> 5;
            int c = idx & 31;
            uint32_t uv = *reinterpret_cast<const uint32_t*>(&Tb[tidx(n, c * 2)]);
            *reinterpret_cast<uint32_t*>(Pg + (size_t)n * CH + c * 2) = uv;
        }
    }
    __syncthreads();

    // vo GEMM: vo[m,h] = S[m,:] . wvoT[h,:] + bvo[h]  (A-frags reused from regs)
#pragma unroll
    for (int nt = 0; nt < 16; ++nt) {
        f32x4 a = {0.f, 0.f, 0.f, 0.f};
        const __bf16* wr = wvoT + (size_t)(nt * 16 + ln) * DD + q * 8;
#pragma unroll
        for (int kk = 0; kk < 8; ++kk) {
            bf16x8 bf = *reinterpret_cast<const bf16x8*>(wr + kk * 32);
            a = mfma_bf16(af[kk], bf, a);
        }
        float bb = bvo[nt * 16 + ln];
        bf16x4 pv = { (__bf16)(a.x + bb), (__bf16)(a.y + bb),
                      (__bf16)(a.z + bb), (__bf16)(a.w + bb) };
        *reinterpret_cast<bf16x4*>(&Tb[tidx(nt * 16 + ln, mr + q * 4)]) = pv;
    }
    __syncthreads();
    {   // flush VO^T tile
        __bf16* Vg = VOT + (m0 - c0);
        for (int it = 0; it < 32; ++it) {
            int idx = it * 256 + t;
            int n = idx >> 5;
            int c = idx & 31;
            uint32_t uv = *reinterpret_cast<const uint32_t*>(&Tb[tidx(n, c * 2)]);
            *reinterpret_cast<uint32_t*>(Vg + (size_t)n * CH + c * 2) = uv;
        }
    }
}

// ---------------- phase B: out_acc[n,h] += P^T @ VO  (K = edge dim) ----------------
// Grid (4 tile-WGs, CH/1024 K-chunks). WG = 4 waves in 2x2; wave does 64x64.
__global__ __launch_bounds__(256)
void phaseB_kernel(const __bf16* __restrict__ PT, const __bf16* __restrict__ VOT,
                   float* __restrict__ accg, int b, int CH) {
    const int t = threadIdx.x;
    const int w = t >> 6;
    const int lane = t & 63;
    const int q = lane >> 4;
    const int ln = lane & 15;
    const int n0 = (blockIdx.x >> 1) * 128 + (w >> 1) * 64;
    const int h0 = (blockIdx.x & 1) * 128 + (w & 1) * 64;
    const size_t mb = (size_t)blockIdx.y * 1024 + q * 8;

    f32x4 acc[16];
#pragma unroll
    for (int i = 0; i < 16; ++i) acc[i] = (f32x4){0.f, 0.f, 0.f, 0.f};

    const __bf16* Pb = PT + mb;
    const __bf16* Vb = VOT + mb;
    for (int ks = 0; ks < 32; ++ks) {
        bf16x8 a[4], bb[4];
#pragma unroll
        for (int i = 0; i < 4; ++i)
            a[i] = *reinterpret_cast<const bf16x8*>(Pb + (size_t)(n0 + i * 16 + ln) * CH + ks * 32);
#pragma unroll
        for (int j = 0; j < 4; ++j)
            bb[j] = *reinterpret_cast<const bf16x8*>(Vb + (size_t)(h0 + j * 16 + ln) * CH + ks * 32);
#pragma unroll
        for (int i = 0; i < 4; ++i)
#pragma unroll
            for (int j = 0; j < 4; ++j)
                acc[i * 4 + j] = mfma_bf16(a[i], bb[j], acc[i * 4 + j]);
    }
    float* og = accg + (size_t)b * NN * DD;
#pragma unroll
    for (int i = 0; i < 4; ++i)
#pragma unroll
        for (int j = 0; j < 4; ++j) {
            f32x4 a = acc[i * 4 + j];
            int n = n0 + i * 16 + q * 4;
            int h = h0 + j * 16 + ln;
            atomicAdd(&og[(size_t)(n + 0) * DD + h], a.x);
            atomicAdd(&og[(size_t)(n + 1) * DD + h], a.y);
            atomicAdd(&og[(size_t)(n + 2) * DD + h], a.z);
            atomicAdd(&og[(size_t)(n + 3) * DD + h], a.w);
        }
}

// ---------------- epilogue: +bo, +residual, LayerNorm ----------------
__global__ void epilogue_kernel(const float* __restrict__ accg, const float* __restrict__ hs,
                                const float* __restrict__ bo, const float* __restrict__ g,
                                const float* __restrict__ be, float* __restrict__ out) {
    const int row = blockIdx.x, t = threadIdx.x;
    __shared__ float red[256];
    const size_t base = (size_t)row * 256;
    float x = accg[base + t] + bo[t] + hs[base + t];
    red[t] = x;
    __syncthreads();
    for (int s = 128; s > 0; s >>= 1) {
        if (t < s) red[t] += red[t + s];
        __syncthreads();
    }
    float mean = red[0] * (1.f / 256.f);
    __syncthreads();
    float d = x - mean;
    red[t] = d * d;
    __syncthreads();
    for (int s = 128; s > 0; s >>= 1) {
        if (t < s) red[t] += red[t + s];
        __syncthreads();
    }
    float var = red[0] * (1.f / 256.f);
    out[base + t] = g[t] * d * rsqrtf(var + 1e-5f) + be[t];
}

// ---------------- host launch ----------------
extern "C" void kernel_launch(void* const* d_in, const int* in_sizes, int n_in,
                              void* d_out, int out_size, void* d_ws, size_t ws_size,
                              hipStream_t stream) {
    const float* hs   = (const float*)d_in[0];
    const float* S    = (const float*)d_in[1];
    const float* mask = (const float*)d_in[2];
    const float* Wq   = (const float*)d_in[3];
    const float* bq   = (const float*)d_in[4];
    const float* Wk   = (const float*)d_in[5];
    const float* bk   = (const float*)d_in[6];
    const float* Wv   = (const float*)d_in[7];
    const float* bv   = (const float*)d_in[8];
    const float* Wo   = (const float*)d_in[9];
    const float* bo   = (const float*)d_in[10];
    const float* g    = (const float*)d_in[11];
    const float* be   = (const float*)d_in[12];
    float* out = (float*)d_out;

    char* ws = (char*)d_ws;
    size_t off = 0;
    auto alloc = [&](size_t bytes) {
        void* p = ws + off;
        off += (bytes + 255) & ~(size_t)255;
        return p;
    };
    float*  accg = (float*)alloc((size_t)NB * NN * DD * 4);
    float*  kf   = (float*)alloc((size_t)NB * NN * DD * 4);
    __bf16* kq   = (__bf16*)alloc((size_t)NB * NN * DD * 2);
    float*  cb   = (float*)alloc((size_t)NB * NN * 4);
    __bf16* wvoT = (__bf16*)alloc((size_t)NN * DD * 2);
    float*  bvo  = (float*)alloc((size_t)NN * 4);
    // pick the largest per-batch edge-chunk that fits the workspace
    size_t rem = ws_size > off ? ws_size - off : 0;
    int CH = MM;
    while (CH > 4096 && (size_t)CH * NN * 2 * 2 + 1024 > rem) CH >>= 1;
    __bf16* PT  = (__bf16*)alloc((size_t)CH * NN * 2);
    __bf16* VOT = (__bf16*)alloc((size_t)CH * NN * 2);

    zero_kernel<<<256, 256, 0, stream>>>(accg);
    kproj_kernel<<<NB * NN, 256, 0, stream>>>(hs, Wk, bk, kf);
    kqprep_kernel<<<NB * NN, 256, 0, stream>>>(kf, Wq, bq, kq, cb);
    wvoprep_kernel<<<NN, 256, 0, stream>>>(Wv, Wo, bv, wvoT, bvo);
    for (int b = 0; b < NB; ++b) {
        for (int c0 = 0; c0 < MM; c0 += CH) {
            phaseA_kernel<<<dim3(CH / 64), 256, 0, stream>>>(S, kq, cb, wvoT, bvo, mask,
                                                             PT, VOT, b, c0, CH);
            phaseB_kernel<<<dim3(4, CH / 1024), 256, 0, stream>>>(PT, VOT, accg, b, CH);
        }
    }
    epilogue_kernel<<<NB * NN, 256, 0, stream>>>(accg, hs, bo, g, be, out);
}

// Round 2
// 1056.538 us; speedup vs baseline: 1.0231x; 1.0231x over previous
//
#include <hip/hip_runtime.h>
#include <hip/hip_bf16.h>
#include <stdint.h>

// B=4, N=256, H=D=256.  M = N*N = 65536 edges per batch.
#define NB 4
#define NN 256
#define DD 256
#define MM 65536

typedef __attribute__((ext_vector_type(8))) __bf16 bf16x8;
typedef __attribute__((ext_vector_type(4))) __bf16 bf16x4;
typedef __attribute__((ext_vector_type(4))) float f32x4;

__device__ __forceinline__ f32x4 mfma_bf16(bf16x8 a, bf16x8 b, f32x4 c) {
    return __builtin_amdgcn_mfma_f32_16x16x32_bf16(a, b, c, 0, 0, 0);
}

// XOR-swizzled LDS indices (8-element groups xor'd by low-3 bits of row) so
// b128 fragment reads and transpose writes are conflict-free without padding.
__device__ __forceinline__ int sidx2(int row, int e) {     // Sb[64][256]
    return row * 256 + (((e >> 3) ^ (row & 7)) << 3) + (e & 7);
}
__device__ __forceinline__ int tidx(int n, int m) {        // Tb[256][64]
    return n * 64 + (((m >> 3) ^ (n & 7)) << 3) + (m & 7);
}

// ---------------- tiny precompute kernels ----------------

__global__ void zero_kernel(float* __restrict__ p) {
    reinterpret_cast<float4*>(p)[blockIdx.x * 256 + threadIdx.x] =
        make_float4(0.f, 0.f, 0.f, 0.f);
}

// fused: k = hs@Wk + bk ; kq[row,e] = (Wq[e,:].k)/16 ; cb[row] = (bq.k)/16
__global__ void kkq_kernel(const float* __restrict__ hs, const float* __restrict__ Wk,
                           const float* __restrict__ bk, const float* __restrict__ Wq,
                           const float* __restrict__ bq, __bf16* __restrict__ kq,
                           float* __restrict__ cb) {
    const int row = blockIdx.x, t = threadIdx.x;
    __shared__ float hr[256];
    __shared__ float kr[256];
    __shared__ float red[256];
    hr[t] = hs[(size_t)row * 256 + t];
    __syncthreads();
    float v = bk[t];
    for (int e = 0; e < 256; ++e)
        v = fmaf(hr[e], Wk[(size_t)e * 256 + t], v);
    kr[t] = v;
    red[t] = v * bq[t];
    __syncthreads();
    float u = 0.f;
    for (int d = 0; d < 256; ++d)
        u = fmaf(Wq[(size_t)t * 256 + d], kr[d], u);
    kq[(size_t)row * 256 + t] = (__bf16)(u * 0.0625f);
    for (int s = 128; s > 0; s >>= 1) {
        if (t < s) red[t] += red[t + s];
        __syncthreads();
    }
    if (t == 0) cb[row] = red[0] * 0.0625f;
}

// wvoT[h,e] = sum_d Wv[e,d] * Wo[d,h] ;  bvo[h] = sum_d bv[d] * Wo[d,h]
__global__ void wvoprep_kernel(const float* __restrict__ Wv, const float* __restrict__ Wo,
                               const float* __restrict__ bv, __bf16* __restrict__ wvoT,
                               float* __restrict__ bvo) {
    const int h = blockIdx.x, t = threadIdx.x;
    __shared__ float woc[256];
    __shared__ float red[256];
    float wo = Wo[(size_t)t * 256 + h];
    woc[t] = wo;
    red[t] = bv[t] * wo;
    __syncthreads();
    float v = 0.f;
    for (int d = 0; d < 256; ++d)
        v = fmaf(Wv[(size_t)t * 256 + d], woc[d], v);
    wvoT[(size_t)h * 256 + t] = (__bf16)v;
    for (int s = 128; s > 0; s >>= 1) {
        if (t < s) red[t] += red[t + s];
        __syncthreads();
    }
    if (t == 0) bvo[h] = red[0];
}

// ---------------- phase A ----------------
// Writes PT[n][m] = relu(scores)[m][n] (UN-normalized, bf16) and
// VOT[h][m] = inv[m] * vo[m][h] (normalizer folded into VO rows).
// One WG = 4 waves = 64 edge-rows; wave w owns rows [w*16, w*16+16).
__global__ __launch_bounds__(256, 2)
void phaseA_kernel(const float* __restrict__ S, const __bf16* __restrict__ kq,
                   const float* __restrict__ cb, const __bf16* __restrict__ wvoT,
                   const float* __restrict__ bvo, const float* __restrict__ mask,
                   __bf16* __restrict__ PT, __bf16* __restrict__ VOT,
                   int c0, int CHS) {
    __shared__ __align__(16) __bf16 Sb[64 * 256];   // 32 KB (A tile, bf16)
    __shared__ __align__(16) __bf16 Tb[256 * 64];   // 32 KB (transpose staging)
    const int t = threadIdx.x;
    const int b = blockIdx.y;
    const int w = t >> 6;
    const int lane = t & 63;
    const int q = lane >> 4;
    const int ln = lane & 15;
    const int m0 = c0 + blockIdx.x * 64;

    // stage S tile (64 x 256) -> bf16 LDS, coalesced float4 loads
    const float* Sg = S + ((size_t)b * MM + m0) * DD;
    for (int it = 0; it < 16; ++it) {
        int idx = it * 256 + t;
        int row = idx >> 6;
        int c4 = idx & 63;
        float4 v = reinterpret_cast<const float4*>(Sg)[row * 64 + c4];
        bf16x4 bv = { (__bf16)v.x, (__bf16)v.y, (__bf16)v.z, (__bf16)v.w };
        *reinterpret_cast<bf16x4*>(&Sb[sidx2(row, c4 * 4)]) = bv;
    }
    __syncthreads();

    const int mr = w * 16;
    bf16x8 af[8];
#pragma unroll
    for (int kk = 0; kk < 8; ++kk)
        af[kk] = *reinterpret_cast<const bf16x8*>(&Sb[sidx2(mr + ln, kk * 32 + q * 8)]);

    // pairwise additive mask for this lane's 4 m-rows
    float m2[4];
#pragma unroll
    for (int r = 0; r < 4; ++r) {
        int mg = m0 + mr + q * 4 + r;
        m2[r] = mask[b * NN + (mg >> 8)] * mask[b * NN + (mg & 255)];
    }

    // scores GEMM: one acc tile live at a time; relu'd tile -> Tb immediately
    float rs0 = 0.f, rs1 = 0.f, rs2 = 0.f, rs3 = 0.f;
    const __bf16* kqb = kq + (size_t)b * NN * DD + (size_t)ln * DD + q * 8;
    const float* cbb = cb + b * NN + ln;
#pragma unroll 2
    for (int nt = 0; nt < 16; ++nt) {
        f32x4 a = {0.f, 0.f, 0.f, 0.f};
        const __bf16* kqr = kqb + (size_t)nt * 16 * DD;
#pragma unroll
        for (int kk = 0; kk < 8; ++kk) {
            bf16x8 bf = *reinterpret_cast<const bf16x8*>(kqr + kk * 32);
            a = mfma_bf16(af[kk], bf, a);
        }
        float cbv = cbb[nt * 16];
        a.x = fmaxf(a.x + cbv + m2[0], 0.f);
        a.y = fmaxf(a.y + cbv + m2[1], 0.f);
        a.z = fmaxf(a.z + cbv + m2[2], 0.f);
        a.w = fmaxf(a.w + cbv + m2[3], 0.f);
        rs0 += a.x; rs1 += a.y; rs2 += a.z; rs3 += a.w;
        bf16x4 pv = { (__bf16)a.x, (__bf16)a.y, (__bf16)a.z, (__bf16)a.w };
        *reinterpret_cast<bf16x4*>(&Tb[tidx(nt * 16 + ln, mr + q * 4)]) = pv;
    }
#pragma unroll
    for (int off = 1; off < 16; off <<= 1) {   // reduce over the 16 n-lanes
        rs0 += __shfl_xor(rs0, off);
        rs1 += __shfl_xor(rs1, off);
        rs2 += __shfl_xor(rs2, off);
        rs3 += __shfl_xor(rs3, off);
    }
    // ref: probs / sum(probs + 1e-12) == probs / (rowsum + 256e-12)
    const float i0 = 1.f / (rs0 + 2.56e-10f);
    const float i1 = 1.f / (rs1 + 2.56e-10f);
    const float i2 = 1.f / (rs2 + 2.56e-10f);
    const float i3 = 1.f / (rs3 + 2.56e-10f);
    __syncthreads();

    {   // flush P^T tile: 16 B/thread, 8 iterations
        __bf16* Pg = PT + (size_t)b * NN * CHS + (m0 - c0);
        for (int it = 0; it < 8; ++it) {
            int idx = it * 256 + t;
            int n = idx >> 3;
            int c = idx & 7;            // m-group of 8
            bf16x8 uv = *reinterpret_cast<const bf16x8*>(&Tb[tidx(n, c * 8)]);
            *reinterpret_cast<bf16x8*>(Pg + (size_t)n * CHS + c * 8) = uv;
        }
    }
    __syncthreads();

    // vo GEMM: vo[m,h] = S[m,:].wvoT[h,:] + bvo[h], scaled by inv[m]
    const __bf16* wvb = wvoT + (size_t)ln * DD + q * 8;
#pragma unroll 2
    for (int nt = 0; nt < 16; ++nt) {
        f32x4 a = {0.f, 0.f, 0.f, 0.f};
        const __bf16* wr = wvb + (size_t)nt * 16 * DD;
#pragma unroll
        for (int kk = 0; kk < 8; ++kk) {
            bf16x8 bf = *reinterpret_cast<const bf16x8*>(wr + kk * 32);
            a = mfma_bf16(af[kk], bf, a);
        }
        float bb = bvo[nt * 16 + ln];
        bf16x4 pv = { (__bf16)((a.x + bb) * i0), (__bf16)((a.y + bb) * i1),
                      (__bf16)((a.z + bb) * i2), (__bf16)((a.w + bb) * i3) };
        *reinterpret_cast<bf16x4*>(&Tb[tidx(nt * 16 + ln, mr + q * 4)]) = pv;
    }
    __syncthreads();
    {   // flush VO^T tile
        __bf16* Vg = VOT + (size_t)b * NN * CHS + (m0 - c0);
        for (int it = 0; it < 8; ++it) {
            int idx = it * 256 + t;
            int n = idx >> 3;
            int c = idx & 7;
            bf16x8 uv = *reinterpret_cast<const bf16x8*>(&Tb[tidx(n, c * 8)]);
            *reinterpret_cast<bf16x8*>(Vg + (size_t)n * CHS + c * 8) = uv;
        }
    }
}

// ---------------- phase B: out_acc[n,h] += P^T @ VO  (K = edge dim) ----------------
// Grid (4 nh-tiles, CHS/2048 K-chunks, NB batches). WG = 4 waves in 2x2.
__global__ __launch_bounds__(256)
void phaseB_kernel(const __bf16* __restrict__ PT, const __bf16* __restrict__ VOT,
                   float* __restrict__ accg, int CHS) {
    const int t = threadIdx.x;
    const int b = blockIdx.z;
    const int w = t >> 6;
    const int lane = t & 63;
    const int q = lane >> 4;
    const int ln = lane & 15;
    const int n0 = (blockIdx.x >> 1) * 128 + (w >> 1) * 64;
    const int h0 = (blockIdx.x & 1) * 128 + (w & 1) * 64;
    const size_t mb = (size_t)blockIdx.y * 2048 + q * 8;

    f32x4 acc[16];
#pragma unroll
    for (int i = 0; i < 16; ++i) acc[i] = (f32x4){0.f, 0.f, 0.f, 0.f};

    const __bf16* Pb = PT + (size_t)b * NN * CHS + mb;
    const __bf16* Vb = VOT + (size_t)b * NN * CHS + mb;
    for (int ks = 0; ks < 64; ++ks) {
        bf16x8 a[4], bb[4];
#pragma unroll
        for (int i = 0; i < 4; ++i)
            a[i] = *reinterpret_cast<const bf16x8*>(Pb + (size_t)(n0 + i * 16 + ln) * CHS + ks * 32);
#pragma unroll
        for (int j = 0; j < 4; ++j)
            bb[j] = *reinterpret_cast<const bf16x8*>(Vb + (size_t)(h0 + j * 16 + ln) * CHS + ks * 32);
#pragma unroll
        for (int i = 0; i < 4; ++i)
#pragma unroll
            for (int j = 0; j < 4; ++j)
                acc[i * 4 + j] = mfma_bf16(a[i], bb[j], acc[i * 4 + j]);
    }
    float* og = accg + (size_t)b * NN * DD;
#pragma unroll
    for (int i = 0; i < 4; ++i)
#pragma unroll
        for (int j = 0; j < 4; ++j) {
            f32x4 a = acc[i * 4 + j];
            int n = n0 + i * 16 + q * 4;
            int h = h0 + j * 16 + ln;
            atomicAdd(&og[(size_t)(n + 0) * DD + h], a.x);
            atomicAdd(&og[(size_t)(n + 1) * DD + h], a.y);
            atomicAdd(&og[(size_t)(n + 2) * DD + h], a.z);
            atomicAdd(&og[(size_t)(n + 3) * DD + h], a.w);
        }
}

// ---------------- epilogue: +bo, +residual, LayerNorm ----------------
__global__ void epilogue_kernel(const float* __restrict__ accg, const float* __restrict__ hs,
                                const float* __restrict__ bo, const float* __restrict__ g,
                                const float* __restrict__ be, float* __restrict__ out) {
    const int row = blockIdx.x, t = threadIdx.x;
    __shared__ float red[256];
    const size_t base = (size_t)row * 256;
    float x = accg[base + t] + bo[t] + hs[base + t];
    red[t] = x;
    __syncthreads();
    for (int s = 128; s > 0; s >>= 1) {
        if (t < s) red[t] += red[t + s];
        __syncthreads();
    }
    float mean = red[0] * (1.f / 256.f);
    __syncthreads();
    float d = x - mean;
    red[t] = d * d;
    __syncthreads();
    for (int s = 128; s > 0; s >>= 1) {
        if (t < s) red[t] += red[t + s];
        __syncthreads();
    }
    float var = red[0] * (1.f / 256.f);
    out[base + t] = g[t] * d * rsqrtf(var + 1e-5f) + be[t];
}

// ---------------- host launch ----------------
extern "C" void kernel_launch(void* const* d_in, const int* in_sizes, int n_in,
                              void* d_out, int out_size, void* d_ws, size_t ws_size,
                              hipStream_t stream) {
    const float* hs   = (const float*)d_in[0];
    const float* S    = (const float*)d_in[1];
    const float* mask = (const float*)d_in[2];
    const float* Wq   = (const float*)d_in[3];
    const float* bq   = (const float*)d_in[4];
    const float* Wk   = (const float*)d_in[5];
    const float* bk   = (const float*)d_in[6];
    const float* Wv   = (const float*)d_in[7];
    const float* bv   = (const float*)d_in[8];
    const float* Wo   = (const float*)d_in[9];
    const float* bo   = (const float*)d_in[10];
    const float* g    = (const float*)d_in[11];
    const float* be   = (const float*)d_in[12];
    float* out = (float*)d_out;

    char* ws = (char*)d_ws;
    size_t off = 0;
    auto alloc = [&](size_t bytes) {
        void* p = ws + off;
        off += (bytes + 255) & ~(size_t)255;
        return p;
    };
    float*  accg = (float*)alloc((size_t)NB * NN * DD * 4);
    __bf16* kq   = (__bf16*)alloc((size_t)NB * NN * DD * 2);
    float*  cb   = (float*)alloc((size_t)NB * NN * 4);
    __bf16* wvoT = (__bf16*)alloc((size_t)NN * DD * 2);
    float*  bvo  = (float*)alloc((size_t)NN * 4);
    // largest per-batch edge-chunk that fits: PT+VOT = 2 * NB * CH * NN * 2 B
    size_t rem = ws_size > off ? ws_size - off : 0;
    int CH = MM;
    while (CH > 4096 && (size_t)CH * 4096 + 1024 > rem) CH >>= 1;
    __bf16* PT  = (__bf16*)alloc((size_t)NB * CH * NN * 2);
    __bf16* VOT = (__bf16*)alloc((size_t)NB * CH * NN * 2);

    zero_kernel<<<256, 256, 0, stream>>>(accg);
    kkq_kernel<<<NB * NN, 256, 0, stream>>>(hs, Wk, bk, Wq, bq, kq, cb);
    wvoprep_kernel<<<NN, 256, 0, stream>>>(Wv, Wo, bv, wvoT, bvo);
    for (int c0 = 0; c0 < MM; c0 += CH) {
        phaseA_kernel<<<dim3(CH / 64, NB), 256, 0, stream>>>(S, kq, cb, wvoT, bvo, mask,
                                                             PT, VOT, c0, CH);
        phaseB_kernel<<<dim3(4, CH / 2048, NB), 256, 0, stream>>>(PT, VOT, accg, CH);
    }
    epilogue_kernel<<<NB * NN, 256, 0, stream>>>(accg, hs, bo, g, be, out);
}

// Round 3
// 672.524 us; speedup vs baseline: 1.6072x; 1.5710x over previous
//
#include <hip/hip_runtime.h>
#include <hip/hip_bf16.h>
#include <stdint.h>

// B=4, N=256, H=D=256.  M = N*N = 65536 edges per batch.
#define NB 4
#define NN 256
#define DD 256
#define MM 65536

typedef __attribute__((ext_vector_type(8))) __bf16 bf16x8;
typedef __attribute__((ext_vector_type(4))) __bf16 bf16x4;
typedef __attribute__((ext_vector_type(4))) float f32x4;

__device__ __forceinline__ f32x4 mfma_bf16(bf16x8 a, bf16x8 b, f32x4 c) {
    return __builtin_amdgcn_mfma_f32_16x16x32_bf16(a, b, c, 0, 0, 0);
}

// fragment-linear index for a [256 rows][256 cols] B-matrix:
// frag (nt,kk), lane (q,ln) holds row nt*16+ln, cols kk*32+q*8..+8
__device__ __forceinline__ size_t fragidx(int row, int col) {
    int nt = row >> 4, ln = row & 15;
    int kk = col >> 5, q = (col >> 3) & 3, e = col & 7;
    return ((size_t)((nt * 8 + kk) * 64 + q * 16 + ln)) * 8 + e;
}

// ---------------- tiny precompute kernels ----------------

__global__ void zero_kernel(float* __restrict__ p) {
    reinterpret_cast<float4*>(p)[blockIdx.x * 256 + threadIdx.x] =
        make_float4(0.f, 0.f, 0.f, 0.f);
}

// fused: k = hs@Wk + bk ; kqf[row,e] = (Wq[e,:].k)/16 (frag-linear) ; cb[row] = (bq.k)/16
__global__ void kkq_kernel(const float* __restrict__ hs, const float* __restrict__ Wk,
                           const float* __restrict__ bk, const float* __restrict__ Wq,
                           const float* __restrict__ bq, __bf16* __restrict__ kqf,
                           float* __restrict__ cb) {
    const int row = blockIdx.x, t = threadIdx.x;   // row in [0, NB*NN)
    __shared__ float hr[256];
    __shared__ float kr[256];
    __shared__ float red[256];
    hr[t] = hs[(size_t)row * 256 + t];
    __syncthreads();
    float v = bk[t];
    for (int e = 0; e < 256; ++e)
        v = fmaf(hr[e], Wk[(size_t)e * 256 + t], v);
    kr[t] = v;
    red[t] = v * bq[t];
    __syncthreads();
    float u = 0.f;
    for (int d = 0; d < 256; ++d)
        u = fmaf(Wq[(size_t)t * 256 + d], kr[d], u);
    const int b = row >> 8, n = row & 255;
    kqf[(size_t)b * NN * DD + fragidx(n, t)] = (__bf16)(u * 0.0625f);
    for (int s = 128; s > 0; s >>= 1) {
        if (t < s) red[t] += red[t + s];
        __syncthreads();
    }
    if (t == 0) cb[row] = red[0] * 0.0625f;
}

// wvof[h,e] = sum_d Wv[e,d]*Wo[d,h] (frag-linear, row=h) ; bvo[h] = bv.Wo[:,h]
__global__ void wvoprep_kernel(const float* __restrict__ Wv, const float* __restrict__ Wo,
                               const float* __restrict__ bv, __bf16* __restrict__ wvof,
                               float* __restrict__ bvo) {
    const int h = blockIdx.x, t = threadIdx.x;
    __shared__ float woc[256];
    __shared__ float red[256];
    float wo = Wo[(size_t)t * 256 + h];
    woc[t] = wo;
    red[t] = bv[t] * wo;
    __syncthreads();
    float v = 0.f;
    for (int d = 0; d < 256; ++d)
        v = fmaf(Wv[(size_t)t * 256 + d], woc[d], v);
    wvof[fragidx(h, t)] = (__bf16)v;
    for (int s = 128; s > 0; s >>= 1) {
        if (t < s) red[t] += red[t + s];
        __syncthreads();
    }
    if (t == 0) bvo[h] = red[0];
}

// ---------------- phase A ----------------
// PT (blocked [m/8][n][8]) = relu(scores)^T un-normalized;
// VOT (same layout)        = (inv[m] * vo[m][h])^T.
// One WG = 4 waves = 64 edge-rows; wave w owns rows [w*16, w*16+16).
__global__ __launch_bounds__(256, 4)
void phaseA_kernel(const float* __restrict__ S, const __bf16* __restrict__ kqf,
                   const float* __restrict__ cb, const __bf16* __restrict__ wvof,
                   const float* __restrict__ bvo, const float* __restrict__ mask,
                   __bf16* __restrict__ PT, __bf16* __restrict__ VOT,
                   int c0, int CHS) {
    __shared__ __align__(16) __bf16 Tb[8 * 256 * 8];   // blocked [c][n][8], 32 KB
    const int t = threadIdx.x;
    const int b = blockIdx.y;
    const int w = t >> 6;
    const int lane = t & 63;
    const int q = lane >> 4;
    const int ln = lane & 15;
    const int m0 = c0 + blockIdx.x * 64;
    const int mr = w * 16;

    // A-fragments straight from global fp32 (rows m0+mr+ln), convert to bf16
    const float* Ar = S + ((size_t)b * MM + m0 + mr + ln) * DD + q * 8;
    bf16x8 af[8];
#pragma unroll
    for (int kk = 0; kk < 8; ++kk) {
        float4 u0 = *reinterpret_cast<const float4*>(Ar + kk * 32);
        float4 u1 = *reinterpret_cast<const float4*>(Ar + kk * 32 + 4);
        af[kk] = (bf16x8){(__bf16)u0.x, (__bf16)u0.y, (__bf16)u0.z, (__bf16)u0.w,
                          (__bf16)u1.x, (__bf16)u1.y, (__bf16)u1.z, (__bf16)u1.w};
    }

    // pairwise additive mask for this lane's 4 m-rows
    float m2[4];
#pragma unroll
    for (int r = 0; r < 4; ++r) {
        int mg = m0 + mr + q * 4 + r;
        m2[r] = mask[b * NN + (mg >> 8)] * mask[b * NN + (mg & 255)];
    }

    const int cblk = (mr >> 3) + (q >> 1);      // this lane's Tb block
    const int coff = (q & 1) * 4;
    // scores GEMM; relu'd tile -> Tb immediately (one acc tile live)
    float rs0 = 0.f, rs1 = 0.f, rs2 = 0.f, rs3 = 0.f;
    const __bf16* kqb = kqf + (size_t)b * NN * DD + (size_t)lane * 8;
    const float* cbb = cb + b * NN + ln;
#pragma unroll 2
    for (int nt = 0; nt < 16; ++nt) {
        f32x4 a = {0.f, 0.f, 0.f, 0.f};
        const __bf16* kr = kqb + (size_t)nt * 4096;
#pragma unroll
        for (int kk = 0; kk < 8; ++kk) {
            bf16x8 bf = *reinterpret_cast<const bf16x8*>(kr + kk * 512);
            a = mfma_bf16(af[kk], bf, a);
        }
        float cbv = cbb[nt * 16];
        a.x = fmaxf(a.x + cbv + m2[0], 0.f);
        a.y = fmaxf(a.y + cbv + m2[1], 0.f);
        a.z = fmaxf(a.z + cbv + m2[2], 0.f);
        a.w = fmaxf(a.w + cbv + m2[3], 0.f);
        rs0 += a.x; rs1 += a.y; rs2 += a.z; rs3 += a.w;
        bf16x4 pv = { (__bf16)a.x, (__bf16)a.y, (__bf16)a.z, (__bf16)a.w };
        *reinterpret_cast<bf16x4*>(&Tb[(size_t)(cblk * 256 + nt * 16 + ln) * 8 + coff]) = pv;
    }
#pragma unroll
    for (int off = 1; off < 16; off <<= 1) {   // reduce over the 16 n-lanes
        rs0 += __shfl_xor(rs0, off);
        rs1 += __shfl_xor(rs1, off);
        rs2 += __shfl_xor(rs2, off);
        rs3 += __shfl_xor(rs3, off);
    }
    // ref: probs / sum(probs + 1e-12) == probs / (rowsum + 256e-12)
    const float i0 = 1.f / (rs0 + 2.56e-10f);
    const float i1 = 1.f / (rs1 + 2.56e-10f);
    const float i2 = 1.f / (rs2 + 2.56e-10f);
    const float i3 = 1.f / (rs3 + 2.56e-10f);
    __syncthreads();

    {   // flush P^T: Tb and destination are both linear in idx -> pure stream
        __bf16* Pg = PT + (size_t)b * NN * CHS + (size_t)(m0 - c0) * 256;
        const __bf16* Ts = Tb;
#pragma unroll
        for (int it = 0; it < 8; ++it) {
            int idx = it * 256 + t;
            *reinterpret_cast<bf16x8*>(Pg + (size_t)idx * 8) =
                *reinterpret_cast<const bf16x8*>(Ts + (size_t)idx * 8);
        }
    }
    __syncthreads();

    // vo GEMM: vo[m,h] = S[m,:].wvo[h,:] + bvo[h], scaled by inv[m]
    const __bf16* wvb = wvof + (size_t)lane * 8;
#pragma unroll 2
    for (int nt = 0; nt < 16; ++nt) {
        f32x4 a = {0.f, 0.f, 0.f, 0.f};
        const __bf16* wr = wvb + (size_t)nt * 4096;
#pragma unroll
        for (int kk = 0; kk < 8; ++kk) {
            bf16x8 bf = *reinterpret_cast<const bf16x8*>(wr + kk * 512);
            a = mfma_bf16(af[kk], bf, a);
        }
        float bb = bvo[nt * 16 + ln];
        bf16x4 pv = { (__bf16)((a.x + bb) * i0), (__bf16)((a.y + bb) * i1),
                      (__bf16)((a.z + bb) * i2), (__bf16)((a.w + bb) * i3) };
        *reinterpret_cast<bf16x4*>(&Tb[(size_t)(cblk * 256 + nt * 16 + ln) * 8 + coff]) = pv;
    }
    __syncthreads();
    {   // flush VO^T
        __bf16* Vg = VOT + (size_t)b * NN * CHS + (size_t)(m0 - c0) * 256;
        const __bf16* Ts = Tb;
#pragma unroll
        for (int it = 0; it < 8; ++it) {
            int idx = it * 256 + t;
            *reinterpret_cast<bf16x8*>(Vg + (size_t)idx * 8) =
                *reinterpret_cast<const bf16x8*>(Ts + (size_t)idx * 8);
        }
    }
}

// ---------------- phase B: out_acc[n,h] += P^T @ VO  (K = edge dim) ----------------
// Blocked layout makes every fragment load a coalesced 256-B segment; no LDS.
// Grid (4 nh-tiles, CHS/2048 K-chunks, NB). WG = 4 waves in 2x2; wave = 64x64.
__global__ __launch_bounds__(256, 2)
void phaseB_kernel(const __bf16* __restrict__ PT, const __bf16* __restrict__ VOT,
                   float* __restrict__ accg, int CHS) {
    const int t = threadIdx.x;
    const int b = blockIdx.z;
    const int w = t >> 6;
    const int lane = t & 63;
    const int q = lane >> 4;
    const int ln = lane & 15;
    const int n0 = (blockIdx.x >> 1) * 128 + (w >> 1) * 64;
    const int h0 = (blockIdx.x & 1) * 128 + (w & 1) * 64;
    const int g0 = blockIdx.y * 256;           // k-chunk of 2048 -> 256 blocks of 8

    f32x4 acc[16];
#pragma unroll
    for (int i = 0; i < 16; ++i) acc[i] = (f32x4){0.f, 0.f, 0.f, 0.f};

    const __bf16* Pb = PT + (size_t)b * NN * CHS;
    const __bf16* Vb = VOT + (size_t)b * NN * CHS;
#pragma unroll 2
    for (int ks = 0; ks < 64; ++ks) {
        const __bf16* Pk = Pb + ((size_t)(g0 + ks * 4 + q) * 256 + n0 + ln) * 8;
        const __bf16* Vk = Vb + ((size_t)(g0 + ks * 4 + q) * 256 + h0 + ln) * 8;
        bf16x8 a[4], bb[4];
#pragma unroll
        for (int i = 0; i < 4; ++i)
            a[i] = *reinterpret_cast<const bf16x8*>(Pk + i * 128);
#pragma unroll
        for (int j = 0; j < 4; ++j)
            bb[j] = *reinterpret_cast<const bf16x8*>(Vk + j * 128);
#pragma unroll
        for (int i = 0; i < 4; ++i)
#pragma unroll
            for (int j = 0; j < 4; ++j)
                acc[i * 4 + j] = mfma_bf16(a[i], bb[j], acc[i * 4 + j]);
    }
    float* og = accg + (size_t)b * NN * DD;
#pragma unroll
    for (int i = 0; i < 4; ++i)
#pragma unroll
        for (int j = 0; j < 4; ++j) {
            f32x4 a = acc[i * 4 + j];
            int n = n0 + i * 16 + q * 4;
            int h = h0 + j * 16 + ln;
            atomicAdd(&og[(size_t)(n + 0) * DD + h], a.x);
            atomicAdd(&og[(size_t)(n + 1) * DD + h], a.y);
            atomicAdd(&og[(size_t)(n + 2) * DD + h], a.z);
            atomicAdd(&og[(size_t)(n + 3) * DD + h], a.w);
        }
}

// ---------------- epilogue: +bo, +residual, LayerNorm ----------------
__global__ void epilogue_kernel(const float* __restrict__ accg, const float* __restrict__ hs,
                                const float* __restrict__ bo, const float* __restrict__ g,
                                const float* __restrict__ be, float* __restrict__ out) {
    const int row = blockIdx.x, t = threadIdx.x;
    __shared__ float red[256];
    const size_t base = (size_t)row * 256;
    float x = accg[base + t] + bo[t] + hs[base + t];
    red[t] = x;
    __syncthreads();
    for (int s = 128; s > 0; s >>= 1) {
        if (t < s) red[t] += red[t + s];
        __syncthreads();
    }
    float mean = red[0] * (1.f / 256.f);
    __syncthreads();
    float d = x - mean;
    red[t] = d * d;
    __syncthreads();
    for (int s = 128; s > 0; s >>= 1) {
        if (t < s) red[t] += red[t + s];
        __syncthreads();
    }
    float var = red[0] * (1.f / 256.f);
    out[base + t] = g[t] * d * rsqrtf(var + 1e-5f) + be[t];
}

// ---------------- host launch ----------------
extern "C" void kernel_launch(void* const* d_in, const int* in_sizes, int n_in,
                              void* d_out, int out_size, void* d_ws, size_t ws_size,
                              hipStream_t stream) {
    const float* hs   = (const float*)d_in[0];
    const float* S    = (const float*)d_in[1];
    const float* mask = (const float*)d_in[2];
    const float* Wq   = (const float*)d_in[3];
    const float* bq   = (const float*)d_in[4];
    const float* Wk   = (const float*)d_in[5];
    const float* bk   = (const float*)d_in[6];
    const float* Wv   = (const float*)d_in[7];
    const float* bv   = (const float*)d_in[8];
    const float* Wo   = (const float*)d_in[9];
    const float* bo   = (const float*)d_in[10];
    const float* g    = (const float*)d_in[11];
    const float* be   = (const float*)d_in[12];
    float* out = (float*)d_out;

    char* ws = (char*)d_ws;
    size_t off = 0;
    auto alloc = [&](size_t bytes) {
        void* p = ws + off;
        off += (bytes + 255) & ~(size_t)255;
        return p;
    };
    float*  accg = (float*)alloc((size_t)NB * NN * DD * 4);
    __bf16* kqf  = (__bf16*)alloc((size_t)NB * NN * DD * 2);
    float*  cb   = (float*)alloc((size_t)NB * NN * 4);
    __bf16* wvof = (__bf16*)alloc((size_t)NN * DD * 2);
    float*  bvo  = (float*)alloc((size_t)NN * 4);
    // largest per-batch edge-chunk that fits: PT+VOT = 2 * NB * CH * NN * 2 B
    size_t rem = ws_size > off ? ws_size - off : 0;
    int CH = MM;
    while (CH > 4096 && (size_t)CH * 4096 + 1024 > rem) CH >>= 1;
    __bf16* PT  = (__bf16*)alloc((size_t)NB * CH * NN * 2);
    __bf16* VOT = (__bf16*)alloc((size_t)NB * CH * NN * 2);

    zero_kernel<<<256, 256, 0, stream>>>(accg);
    kkq_kernel<<<NB * NN, 256, 0, stream>>>(hs, Wk, bk, Wq, bq, kqf, cb);
    wvoprep_kernel<<<NN, 256, 0, stream>>>(Wv, Wo, bv, wvof, bvo);
    for (int c0 = 0; c0 < MM; c0 += CH) {
        phaseA_kernel<<<dim3(CH / 64, NB), 256, 0, stream>>>(S, kqf, cb, wvof, bvo, mask,
                                                             PT, VOT, c0, CH);
        phaseB_kernel<<<dim3(4, CH / 2048, NB), 256, 0, stream>>>(PT, VOT, accg, CH);
    }
    epilogue_kernel<<<NB * NN, 256, 0, stream>>>(accg, hs, bo, g, be, out);
}